// Round 1
// baseline (596.915 us; speedup 1.0000x reference)
//
#include <hip/hip_runtime.h>

#define NN     200000
#define MPAD   200064   // 1563 * 128
#define KDIM   256
#define NCAT   512
#define NHEAD  8
#define NGRAPH 1024
#define APAD   264      // padded LDS row for alpha kernel

typedef __bf16 bf16x8 __attribute__((ext_vector_type(8)));
typedef float  f32x4  __attribute__((ext_vector_type(4)));

// ---------- helpers ----------
__device__ __forceinline__ unsigned short f2bu(float f) {
    // round-to-nearest-even bf16 (inputs finite)
    unsigned u = __float_as_uint(f);
    unsigned r = (u + 0x7FFFu + ((u >> 16) & 1u)) >> 16;
    return (unsigned short)r;
}
__device__ __forceinline__ float b2f(unsigned short u) {
    return __uint_as_float(((unsigned)u) << 16);
}
__device__ __forceinline__ void async16(const void* g, void* l) {
    __builtin_amdgcn_global_load_lds(
        (const __attribute__((address_space(1))) void*)g,
        (__attribute__((address_space(3))) void*)l, 16, 0, 0);
}

// ---------- kernel 1: cast x -> bf16, zero the 64 pad rows ----------
__global__ __launch_bounds__(256) void convert_x(const float* __restrict__ x,
                                                 unsigned short* __restrict__ xb) {
    size_t e = ((size_t)blockIdx.x * 256 + threadIdx.x) * 4;   // grid sized exactly
    ushort4 o;
    if (e < (size_t)NN * 256) {
        float4 v = *(const float4*)(x + e);
        o.x = f2bu(v.x); o.y = f2bu(v.y); o.z = f2bu(v.z); o.w = f2bu(v.w);
    } else {
        o.x = o.y = o.z = o.w = 0;
    }
    *(ushort4*)(xb + e) = o;
}

// ---------- kernel 2: transpose-convert weights, build concat bias ----------
__global__ __launch_bounds__(256) void convert_w(
    const float* __restrict__ Wg1, const float* __restrict__ Wn1,
    const float* __restrict__ Wn2, const float* __restrict__ bn1,
    unsigned short* __restrict__ wcatT, unsigned short* __restrict__ wn2T,
    float* __restrict__ biascat) {
    int i = blockIdx.x * 256 + threadIdx.x;
    if (i < 512 * 256) {                       // wcatT[n][k] = Wcat[k][n]
        int n = i >> 8, k = i & 255;
        float v = (n < 256) ? Wg1[k * 256 + n] : Wn1[k * 256 + (n - 256)];
        wcatT[i] = f2bu(v);
    } else if (i < 512 * 256 + 256 * 256) {    // wn2T[c][k] = Wn2[k][c]
        int j = i - 512 * 256;
        int n = j >> 8, k = j & 255;
        wn2T[j] = f2bu(Wn2[k * 256 + n]);
    } else if (i < 512 * 256 + 256 * 256 + 512) {
        int b = i - (512 * 256 + 256 * 256);
        biascat[b] = (b < 256) ? 0.0f : bn1[b - 256];
    }
}

// ---------- kernel 3/4: bf16 MFMA GEMM, C = act(A @ Bt^T + bias) ----------
// A: [rows, lda] bf16 row-major.  Bt: [ncols, 256] bf16 (B transposed).
// 128x128 tile, BK=32, 4 waves (2x2), each wave 4x4 of 16x16x32 MFMA.
__global__ __launch_bounds__(256) void gemm_bt(
    const unsigned short* __restrict__ A, int lda,
    const unsigned short* __restrict__ Bt,
    const float* __restrict__ bias,
    unsigned short* __restrict__ C, int ldc, int do_relu) {
    __shared__ unsigned short As[128 * 32];   // no padding: global_load_lds layout
    __shared__ unsigned short Bs[128 * 32];
    const int tid  = threadIdx.x;
    const int lane = tid & 63;
    const int wave = tid >> 6;
    const int wm = wave >> 1, wn = wave & 1;
    const size_t m0 = (size_t)blockIdx.x * 128;
    const int    n0 = blockIdx.y * 128;

    // staging: each wave stages 32 rows of A-tile and 32 rows of Bt-tile
    const int srow = wave * 32 + (lane >> 2);
    const int scol = (lane & 3) * 8;
    const unsigned short* gA0 = A + (m0 + srow) * (size_t)lda + scol;
    const unsigned short* gA1 = gA0 + (size_t)16 * lda;
    const unsigned short* gB0 = Bt + (size_t)(n0 + srow) * KDIM + scol;
    const unsigned short* gB1 = gB0 + 16 * KDIM;
    unsigned short* lA = As + wave * 1024;    // HW adds lane*16B
    unsigned short* lB = Bs + wave * 1024;

    f32x4 acc[4][4] = {};
    const int frow = lane & 15;
    const int koff = (lane >> 4) * 8;
    const int arow = wm * 64 + frow;
    const int brow = wn * 64 + frow;

    for (int k0 = 0; k0 < KDIM; k0 += 32) {
        async16(gA0 + k0, lA);
        async16(gA1 + k0, lA + 512);
        async16(gB0 + k0, lB);
        async16(gB1 + k0, lB + 512);
        __syncthreads();           // drains vmcnt before LDS use
        bf16x8 af[4], bf[4];
        #pragma unroll
        for (int i = 0; i < 4; ++i)
            af[i] = *(const bf16x8*)(As + (arow + i * 16) * 32 + koff);
        #pragma unroll
        for (int j = 0; j < 4; ++j)
            bf[j] = *(const bf16x8*)(Bs + (brow + j * 16) * 32 + koff);
        #pragma unroll
        for (int i = 0; i < 4; ++i)
            #pragma unroll
            for (int j = 0; j < 4; ++j)
                acc[i][j] = __builtin_amdgcn_mfma_f32_16x16x32_bf16(
                    af[i], bf[j], acc[i][j], 0, 0, 0);
        __syncthreads();           // protect LDS before next stage
    }

    float bv[4];
    #pragma unroll
    for (int j = 0; j < 4; ++j) bv[j] = bias[n0 + wn * 64 + j * 16 + frow];
    const int rbase = wm * 64 + ((lane >> 4) << 2);
    #pragma unroll
    for (int i = 0; i < 4; ++i) {
        #pragma unroll
        for (int r = 0; r < 4; ++r) {
            size_t row = m0 + rbase + i * 16 + r;
            #pragma unroll
            for (int j = 0; j < 4; ++j) {
                float v = acc[i][j][r] + bv[j];
                if (do_relu) v = fmaxf(v, 0.0f);
                C[row * ldc + (n0 + wn * 64 + j * 16 + frow)] = f2bu(v);
            }
        }
    }
}

// ---------- kernel 5: alpha = h_g @ Wg2  (fp32 accum, LDS-staged) ----------
__global__ __launch_bounds__(256) void alpha_kernel(
    const unsigned short* __restrict__ h,   // [MPAD,512], cols 0..255 = h_g
    const float* __restrict__ Wg2,          // [256,8] fp32
    float* __restrict__ alpha) {            // [NN,8]
    __shared__ unsigned short hs[64 * APAD];
    __shared__ float wg[256 * 8];
    const int t = threadIdx.x;
    const size_t n0 = (size_t)blockIdx.x * 64;
    for (int i = t; i < 2048; i += 256) wg[i] = Wg2[i];
    #pragma unroll
    for (int it = 0; it < 16; ++it) {
        int e = (t + it * 256) * 4;
        int r = e >> 8, c = e & 255;
        *(ushort4*)&hs[r * APAD + c] = *(const ushort4*)(h + (n0 + r) * 512 + c);
    }
    __syncthreads();
    const int nl = t >> 2;        // node 0..63 (4-way broadcast read: free)
    const int hp = t & 3;         // heads hp, hp+4
    float a0 = 0.f, a1 = 0.f;
    #pragma unroll 8
    for (int k = 0; k < 256; ++k) {
        float xv = b2f(hs[nl * APAD + k]);
        a0 += xv * wg[k * 8 + hp];
        a1 += xv * wg[k * 8 + hp + 4];
    }
    alpha[(n0 + nl) * 8 + hp]     = a0;
    alpha[(n0 + nl) * 8 + hp + 4] = a1;
}

// ---------- kernel 6: per-graph softmax + gated pooling ----------
__device__ __forceinline__ int lower_bound(const int* __restrict__ b, int key) {
    int lo = 0, hi = NN;
    while (lo < hi) { int mid = (lo + hi) >> 1; if (b[mid] < key) lo = mid + 1; else hi = mid; }
    return lo;
}

__global__ __launch_bounds__(256) void pool_kernel(
    const float* __restrict__ alpha, const unsigned short* __restrict__ feats,
    const int* __restrict__ batch, float* __restrict__ out) {
    __shared__ float red[256];
    __shared__ float mh[8], ih[8];
    const int g = blockIdx.x, t = threadIdx.x;
    const int start = lower_bound(batch, g);
    const int end   = lower_bound(batch, g + 1);
    const int hd = t & 7;

    float mloc = -INFINITY;
    for (int n = start + (t >> 3); n < end; n += 32)
        mloc = fmaxf(mloc, alpha[n * 8 + hd]);
    red[t] = mloc; __syncthreads();
    for (int off = 128; off >= 8; off >>= 1) {
        if (t < off) red[t] = fmaxf(red[t], red[t + off]);
        __syncthreads();
    }
    if (t < 8) mh[t] = red[t];
    __syncthreads();
    const float mm = mh[hd];

    float sloc = 0.f;
    for (int n = start + (t >> 3); n < end; n += 32)
        sloc += __expf(alpha[n * 8 + hd] - mm);
    red[t] = sloc; __syncthreads();
    for (int off = 128; off >= 8; off >>= 1) {
        if (t < off) red[t] += red[t + off];
        __syncthreads();
    }
    if (t < 8) ih[t] = 1.0f / (red[t] + 1e-16f);
    __syncthreads();
    const float inv = ih[hd];

    float acc = 0.f;
    for (int n = start; n < end; ++n) {
        float gate = __expf(alpha[n * 8 + hd] - mm) * inv;
        acc += gate * b2f(feats[(size_t)n * 256 + t]);
    }
    out[g * 256 + t] = acc;
}

// ---------- launch ----------
extern "C" void kernel_launch(void* const* d_in, const int* in_sizes, int n_in,
                              void* d_out, int out_size, void* d_ws, size_t ws_size,
                              hipStream_t stream) {
    const float* x     = (const float*)d_in[0];
    const int*   batch = (const int*)d_in[1];
    const float* Wg2   = (const float*)d_in[3];
    const float* bn2   = (const float*)d_in[7];
    float* out = (float*)d_out;

    // ws layout (bf16 buffers as ushort)
    unsigned short* xb    = (unsigned short*)d_ws;            // MPAD*256
    unsigned short* h     = xb + (size_t)MPAD * 256;          // MPAD*512
    unsigned short* feats = h + (size_t)MPAD * 512;           // MPAD*256
    unsigned short* wcatT = feats + (size_t)MPAD * 256;       // 512*256
    unsigned short* wn2T  = wcatT + 512 * 256;                // 256*256
    float* biascat = (float*)(wn2T + 256 * 256);              // 512
    float* alpha   = biascat + 512;                           // NN*8

    convert_x<<<50016, 256, 0, stream>>>(x, xb);
    convert_w<<<770, 256, 0, stream>>>((const float*)d_in[2], (const float*)d_in[4],
                                       (const float*)d_in[6], (const float*)d_in[5],
                                       wcatT, wn2T, biascat);
    // h = relu(x @ [Wg1 | Wn1] + [0 | bn1])   -> [MPAD, 512] bf16
    gemm_bt<<<dim3(1563, 4), 256, 0, stream>>>(xb, 256, wcatT, biascat, h, 512, 1);
    // alpha = h_g @ Wg2
    alpha_kernel<<<3125, 256, 0, stream>>>(h, Wg2, alpha);
    // feats = h_n @ Wn2 + bn2                 -> [MPAD, 256] bf16
    gemm_bt<<<dim3(1563, 2), 256, 0, stream>>>(h + 256, 512, wn2T, bn2, feats, 256, 0);
    // segment softmax + gated pooling
    pool_kernel<<<NGRAPH, 256, 0, stream>>>(alpha, feats, batch, out);
}